// Round 5
// baseline (180.912 us; speedup 1.0000x reference)
//
#include <hip/hip_runtime.h>
#include <math.h>

// Capsule routing, fused, fp32.
// x: [256][1152][8]  W: [1152][10][16][8]
// out: v [256][10][16] (40960) then c_out broadcast [256][1152][10] (2949120)
//
// Strategy (mode 2/1): W' = c_ij ∘ W prescaled+transposed to [k=9216][n=160]
// each routing iteration; s-GEMM streams W' from global/L2 with only x in LDS.
// mode 0 (small ws): legacy LDS-staged k_s.

// ---------------------------------------------------------------------------
// k_scale: Wp[(r*8+i)*160 + c*16+o] = cij[r][c] * W[r][c][o][i]
// grid 576 (2 routes/block), block 256.
__global__ __launch_bounds__(256) void k_scale(const float* __restrict__ W,
                                               const float* __restrict__ cw, // null -> 1/1152
                                               float* __restrict__ Wp)
{
    __shared__ float raw[2560];
    __shared__ float cl[20];
    const int r0 = blockIdx.x * 2;
    const int tid = threadIdx.x;
    if (tid < 20) cl[tid] = cw ? cw[r0 * 10 + tid] : (1.0f / 1152.0f);
    const float4* __restrict__ W4 = reinterpret_cast<const float4*>(W) + (size_t)r0 * 320;
#pragma unroll
    for (int q = 0; q < 3; ++q) {
        const int idx = q * 256 + tid;
        if (idx < 640) *reinterpret_cast<float4*>(&raw[idx * 4]) = W4[idx];
    }
    __syncthreads();
#pragma unroll
    for (int q = 0; q < 10; ++q) {
        const int idx = q * 256 + tid;          // 0..2559
        const int kl = idx / 160, n = idx % 160;
        const int rl = kl >> 3, i = kl & 7, c = n >> 4, o = n & 15;
        Wp[(size_t)(r0 * 8 + kl) * 160 + n] =
            raw[rl * 1280 + c * 128 + o * 8 + i] * cl[rl * 10 + c];
    }
}

// ---------------------------------------------------------------------------
// k_s3: s_part[kb][b][n] = sum_{k in slab} x[b][k] * Wp[k][n]
// M-tile 32, K-slab KR. block 128 = tng(32) x tmg(4); TM=8, TN=5 (n = tng*4+j | 128+tng).
// W' streamed from global (coalesced f4 + b32); x staged once in LDS, no in-loop barriers.
template<int KR>
__global__ __launch_bounds__(128) void k_s3(const float* __restrict__ x,
                                            const float* __restrict__ Wp,
                                            float* __restrict__ s_part)
{
    __shared__ float Xs[32 * KR];               // [m][kk]
    constexpr int KB  = 9216 / KR;
    constexpr int KR4 = KR / 4;
    const int kb = blockIdx.x % KB;
    const int bt = blockIdx.x / KB;
    const int b0 = bt * 32;
    const int tid = threadIdx.x;
    const int tng = tid & 31;
    const int tmg = tid >> 5;

    const float4* __restrict__ X4 = reinterpret_cast<const float4*>(x);
    for (int idx = tid; idx < 32 * KR4; idx += 128) {
        const int bl = idx / KR4, q = idx % KR4;
        *reinterpret_cast<float4*>(&Xs[bl * KR + q * 4]) =
            X4[(size_t)(b0 + bl) * 2304 + kb * KR4 + q];
    }
    __syncthreads();

    float acc[8][5];
#pragma unroll
    for (int a = 0; a < 8; ++a)
#pragma unroll
        for (int j = 0; j < 5; ++j) acc[a][j] = 0.f;

    const float* __restrict__ wb = Wp + (size_t)kb * KR * 160;
    const float4* __restrict__ xs4 = reinterpret_cast<const float4*>(Xs);
    const int mrow = tmg * 8;

#pragma unroll 2
    for (int k4 = 0; k4 < KR4; ++k4) {
        float w[4][5];
#pragma unroll
        for (int u = 0; u < 4; ++u) {
            const int kg = k4 * 4 + u;
            const float4 wv = *reinterpret_cast<const float4*>(&wb[kg * 160 + tng * 4]);
            w[u][0] = wv.x; w[u][1] = wv.y; w[u][2] = wv.z; w[u][3] = wv.w;
            w[u][4] = wb[kg * 160 + 128 + tng];
        }
#pragma unroll
        for (int mi = 0; mi < 8; ++mi) {
            const float4 xv = xs4[(mrow + mi) * KR4 + k4];
#pragma unroll
            for (int j = 0; j < 5; ++j) {
                acc[mi][j] = fmaf(xv.x, w[0][j], acc[mi][j]);
                acc[mi][j] = fmaf(xv.y, w[1][j], acc[mi][j]);
                acc[mi][j] = fmaf(xv.z, w[2][j], acc[mi][j]);
                acc[mi][j] = fmaf(xv.w, w[3][j], acc[mi][j]);
            }
        }
    }

#pragma unroll
    for (int mi = 0; mi < 8; ++mi) {
        float* dst = &s_part[(size_t)(kb * 256 + b0 + mrow + mi) * 160];
        *reinterpret_cast<float4*>(&dst[tng * 4]) =
            make_float4(acc[mi][0], acc[mi][1], acc[mi][2], acc[mi][3]);
        dst[128 + tng] = acc[mi][4];
    }
}

// ---------------------------------------------------------------------------
// k_s_legacy (mode 0 only): LDS-staged c∘W, KB=32. Verbatim R4 structure.
__global__ __launch_bounds__(128) void k_s_legacy(const float* __restrict__ x,
                                                  const float* __restrict__ W,
                                                  const float* __restrict__ cw,
                                                  float* __restrict__ s_part,
                                                  int KB)
{
    __shared__ float Ws[24 * 160];
    __shared__ float Xs[24 * 16];
    __shared__ float cwl[368];
    const int kb = blockIdx.x % KB;
    const int bt = blockIdx.x / KB;
    const int Rslab = 1152 / KB;
    const int nch = Rslab / 3;
    const int r_base = kb * Rslab;
    const int b0 = bt * 16;
    const int tid = threadIdx.x;
    const int tng = tid & 31;
    const int tmg = tid >> 5;

    const float4* __restrict__ W4 = reinterpret_cast<const float4*>(W);
    const float4* __restrict__ X4 = reinterpret_cast<const float4*>(x);
    const float inv1152 = 1.0f / 1152.0f;
    for (int t = tid; t < Rslab * 10; t += 128)
        cwl[t] = cw ? cw[r_base * 10 + t] : inv1152;

    float acc[4][5];
#pragma unroll
    for (int a = 0; a < 4; ++a)
#pragma unroll
        for (int j = 0; j < 5; ++j) acc[a][j] = 0.f;

    float4 wreg[8];
    float4 xreg;
    const int xmi = tid / 6;
    const int xkq = tid % 6;

    auto load_chunk = [&](int ch) {
        const int r0g = r_base + ch * 3;
#pragma unroll
        for (int q = 0; q < 8; ++q) {
            const int idx = q * 128 + tid;
            if (idx < 960) {
                const int rl = idx / 320, rem = idx % 320;
                wreg[q] = W4[(r0g + rl) * 320 + rem];
            }
        }
        if (tid < 96) xreg = X4[(b0 + xmi) * 2304 + r0g * 2 + xkq];
    };
    auto write_chunk = [&](int ch) {
#pragma unroll
        for (int q = 0; q < 8; ++q) {
            const int idx = q * 128 + tid;
            if (idx < 960) {
                const int rl = idx / 320, rem = idx % 320;
                const int h = rem & 1, o = (rem >> 1) & 15, cc = rem >> 5;
                const float sc = cwl[(ch * 3 + rl) * 10 + cc];
                const int kk = rl * 8 + h * 4;
                const int n = cc * 16 + o;
                Ws[(kk + 0) * 160 + n] = wreg[q].x * sc;
                Ws[(kk + 1) * 160 + n] = wreg[q].y * sc;
                Ws[(kk + 2) * 160 + n] = wreg[q].z * sc;
                Ws[(kk + 3) * 160 + n] = wreg[q].w * sc;
            }
        }
        if (tid < 96) {
            Xs[(xkq * 4 + 0) * 16 + xmi] = xreg.x;
            Xs[(xkq * 4 + 1) * 16 + xmi] = xreg.y;
            Xs[(xkq * 4 + 2) * 16 + xmi] = xreg.z;
            Xs[(xkq * 4 + 3) * 16 + xmi] = xreg.w;
        }
    };

    load_chunk(0);
    for (int ch = 0; ch < nch; ++ch) {
        __syncthreads();
        write_chunk(ch);
        __syncthreads();
        if (ch + 1 < nch) load_chunk(ch + 1);
#pragma unroll 6
        for (int kk = 0; kk < 24; ++kk) {
            const float4 xv = *reinterpret_cast<const float4*>(&Xs[kk * 16 + tmg * 4]);
            const float* wr = &Ws[kk * 160 + tng * 5];
            const float w0 = wr[0], w1 = wr[1], w2 = wr[2], w3 = wr[3], w4 = wr[4];
            acc[0][0] = fmaf(xv.x, w0, acc[0][0]);
            acc[0][1] = fmaf(xv.x, w1, acc[0][1]);
            acc[0][2] = fmaf(xv.x, w2, acc[0][2]);
            acc[0][3] = fmaf(xv.x, w3, acc[0][3]);
            acc[0][4] = fmaf(xv.x, w4, acc[0][4]);
            acc[1][0] = fmaf(xv.y, w0, acc[1][0]);
            acc[1][1] = fmaf(xv.y, w1, acc[1][1]);
            acc[1][2] = fmaf(xv.y, w2, acc[1][2]);
            acc[1][3] = fmaf(xv.y, w3, acc[1][3]);
            acc[1][4] = fmaf(xv.y, w4, acc[1][4]);
            acc[2][0] = fmaf(xv.z, w0, acc[2][0]);
            acc[2][1] = fmaf(xv.z, w1, acc[2][1]);
            acc[2][2] = fmaf(xv.z, w2, acc[2][2]);
            acc[2][3] = fmaf(xv.z, w3, acc[2][3]);
            acc[2][4] = fmaf(xv.z, w4, acc[2][4]);
            acc[3][0] = fmaf(xv.w, w0, acc[3][0]);
            acc[3][1] = fmaf(xv.w, w1, acc[3][1]);
            acc[3][2] = fmaf(xv.w, w2, acc[3][2]);
            acc[3][3] = fmaf(xv.w, w3, acc[3][3]);
            acc[3][4] = fmaf(xv.w, w4, acc[3][4]);
        }
    }
#pragma unroll
    for (int mi = 0; mi < 4; ++mi) {
        float* dst = &s_part[(size_t)(kb * 256 + b0 + tmg * 4 + mi) * 160 + tng * 5];
#pragma unroll
        for (int j = 0; j < 5; ++j) dst[j] = acc[mi][j];
    }
}

// ---------------------------------------------------------------------------
// k_red: reduce 8 slabs -> 1 partial, float4 coalesced.
__global__ __launch_bounds__(256) void k_red(const float* __restrict__ s_part,
                                             float* __restrict__ part2, int nsg)
{
    const int eb = blockIdx.x / nsg;
    const int sg = blockIdx.x % nsg;
    const int e4 = eb * 256 + threadIdx.x;
    const float4* __restrict__ sp4 =
        reinterpret_cast<const float4*>(s_part) + (size_t)sg * 8 * 10240 + e4;
    float4 a = sp4[0];
#pragma unroll
    for (int s = 1; s < 8; ++s) {
        const float4 t = sp4[(size_t)s * 10240];
        a.x += t.x; a.y += t.y; a.z += t.z; a.w += t.w;
    }
    reinterpret_cast<float4*>(part2)[(size_t)sg * 10240 + e4] = a;
}

// ---------------------------------------------------------------------------
// k_vfin: sum nsg partials, squash over o (16 consecutive lanes), write v/out.
__global__ __launch_bounds__(256) void k_vfin(const float* __restrict__ part2,
                                              float* __restrict__ dst, int nsg)
{
    const int e = blockIdx.x * 256 + threadIdx.x;
    float s = 0.f;
    for (int g = 0; g < nsg; ++g) s += part2[(size_t)g * 40960 + e];
    float sq = s * s;
#pragma unroll
    for (int off = 1; off < 16; off <<= 1) sq += __shfl_xor(sq, off, 16);
    const float scale = (sq / (1.f + sq)) / sqrtf(sq + 1e-9f);
    dst[e] = s * scale;
}

// ---------------------------------------------------------------------------
// k_copy: broadcast cij [11520] -> out[40960 + b*11520], float4, wide grid.
__global__ __launch_bounds__(256) void k_copy(const float* __restrict__ cij,
                                              float* __restrict__ out)
{
    const int i = blockIdx.x * 256 + threadIdx.x;
    const float4 v = reinterpret_cast<const float4*>(cij)[i % 2880];
    reinterpret_cast<float4*>(out + 40960)[i] = v;
}

// ---------------------------------------------------------------------------
// k_a: dbp[ks][r][c] = sum_{b in quarter} sum_o u_hat[b,r,c,o] * v[b,c,o]
// grid 2304 = mb(576) x ks(4); block 128. No global atomics (k_sm sums the 4 parts).
__global__ __launch_bounds__(128) void k_a(const float* __restrict__ x,
                                           const float* __restrict__ v,
                                           const float* __restrict__ W,
                                           float* __restrict__ dbp)
{
    __shared__ float Xn[64 * 16];
    __shared__ float Vst[32 * 160];
    __shared__ float dbl[20];
    const int mb = blockIdx.x >> 2;
    const int ks = blockIdx.x & 3;
    const int m0 = mb * 16;
    const int r0 = m0 >> 3;
    const int b0 = ks * 64;
    const int tid = threadIdx.x;
    const int tng = tid & 31;
    const int tmg = tid >> 5;
    if (tid < 20) dbl[tid] = 0.f;

    const float4* __restrict__ X4 = reinterpret_cast<const float4*>(x);
    const float4* __restrict__ V4 = reinterpret_cast<const float4*>(v);

#pragma unroll
    for (int q = 0; q < 2; ++q) {
        const int idx = q * 128 + tid;
        const int bb = idx >> 2, qq = idx & 3;
        *reinterpret_cast<float4*>(&Xn[bb * 16 + qq * 4]) =
            X4[(size_t)(b0 + bb) * 2304 + mb * 4 + qq];
    }

    float acc[4][5];
#pragma unroll
    for (int a = 0; a < 4; ++a)
#pragma unroll
        for (int j = 0; j < 5; ++j) acc[a][j] = 0.f;

    for (int bc = 0; bc < 2; ++bc) {
        __syncthreads();
#pragma unroll
        for (int q = 0; q < 10; ++q) {
            const int idx = q * 128 + tid;
            const int bb = idx / 40, nq = idx % 40;
            *reinterpret_cast<float4*>(&Vst[bb * 160 + nq * 4]) =
                V4[(size_t)(b0 + bc * 32 + bb) * 40 + nq];
        }
        __syncthreads();
#pragma unroll 4
        for (int bb = 0; bb < 32; ++bb) {
            const float4 xv = *reinterpret_cast<const float4*>(
                &Xn[(bc * 32 + bb) * 16 + tmg * 4]);
            const float* vr = &Vst[bb * 160 + tng * 5];
            const float v0 = vr[0], v1 = vr[1], v2 = vr[2], v3 = vr[3], v4_ = vr[4];
            acc[0][0] = fmaf(xv.x, v0, acc[0][0]);
            acc[0][1] = fmaf(xv.x, v1, acc[0][1]);
            acc[0][2] = fmaf(xv.x, v2, acc[0][2]);
            acc[0][3] = fmaf(xv.x, v3, acc[0][3]);
            acc[0][4] = fmaf(xv.x, v4_, acc[0][4]);
            acc[1][0] = fmaf(xv.y, v0, acc[1][0]);
            acc[1][1] = fmaf(xv.y, v1, acc[1][1]);
            acc[1][2] = fmaf(xv.y, v2, acc[1][2]);
            acc[1][3] = fmaf(xv.y, v3, acc[1][3]);
            acc[1][4] = fmaf(xv.y, v4_, acc[1][4]);
            acc[2][0] = fmaf(xv.z, v0, acc[2][0]);
            acc[2][1] = fmaf(xv.z, v1, acc[2][1]);
            acc[2][2] = fmaf(xv.z, v2, acc[2][2]);
            acc[2][3] = fmaf(xv.z, v3, acc[2][3]);
            acc[2][4] = fmaf(xv.z, v4_, acc[2][4]);
            acc[3][0] = fmaf(xv.w, v0, acc[3][0]);
            acc[3][1] = fmaf(xv.w, v1, acc[3][1]);
            acc[3][2] = fmaf(xv.w, v2, acc[3][2]);
            acc[3][3] = fmaf(xv.w, v3, acc[3][3]);
            acc[3][4] = fmaf(xv.w, v4_, acc[3][4]);
        }
    }

    const int rl = tmg >> 1;
    const int c0 = (tng * 5) >> 4;
    const int c1 = (tng * 5 + 4) >> 4;
    float p0 = 0.f, p1 = 0.f;
#pragma unroll
    for (int mi = 0; mi < 4; ++mi) {
        const int ml = tmg * 4 + mi;
        const int i = ml & 7;
        const int r = r0 + rl;
#pragma unroll
        for (int j = 0; j < 5; ++j) {
            const int n = tng * 5 + j;
            const int c = n >> 4, o = n & 15;
            const float w = W[(((r * 10 + c) * 16 + o) * 8) + i];
            const float t = w * acc[mi][j];
            if (c == c0) p0 += t; else p1 += t;
        }
    }
    __syncthreads();
    atomicAdd(&dbl[rl * 10 + c0], p0);
    if (c1 != c0) atomicAdd(&dbl[rl * 10 + c1], p1);
    __syncthreads();
    if (tid < 20) dbp[(size_t)ks * 11520 + (r0 + tid / 10) * 10 + (tid % 10)] = dbl[tid];
}

// ---------------------------------------------------------------------------
// k_sm: bnew = bprev + (sum_ks dbp[ks])/256 ; c = softmax over routes per cap
__global__ __launch_bounds__(128) void k_sm(const float* __restrict__ bprev,
                                            const float* __restrict__ dbp,
                                            float* __restrict__ bnew,
                                            float* __restrict__ cij)
{
    __shared__ float red[2];
    __shared__ float red2[2];
    const int c = blockIdx.x;
    const int tid = threadIdx.x;
    float bv[9];
#pragma unroll
    for (int j = 0; j < 9; ++j) {
        const int idx = (tid + j * 128) * 10 + c;
        const float d = dbp[idx] + dbp[11520 + idx] + dbp[23040 + idx] + dbp[34560 + idx];
        bv[j] = (bprev ? bprev[idx] : 0.f) + d * (1.0f / 256.0f);
    }
    float mx = bv[0];
#pragma unroll
    for (int j = 1; j < 9; ++j) mx = fmaxf(mx, bv[j]);
#pragma unroll
    for (int off = 1; off < 64; off <<= 1) mx = fmaxf(mx, __shfl_xor(mx, off, 64));
    if ((tid & 63) == 0) red[tid >> 6] = mx;
    __syncthreads();
    mx = fmaxf(red[0], red[1]);
    float es[9], lsum = 0.f;
#pragma unroll
    for (int j = 0; j < 9; ++j) { es[j] = expf(bv[j] - mx); lsum += es[j]; }
#pragma unroll
    for (int off = 1; off < 64; off <<= 1) lsum += __shfl_xor(lsum, off, 64);
    if ((tid & 63) == 0) red2[tid >> 6] = lsum;
    __syncthreads();
    const float inv = 1.f / (red2[0] + red2[1]);
#pragma unroll
    for (int j = 0; j < 9; ++j) {
        const int idx = (tid + j * 128) * 10 + c;
        bnew[idx] = bv[j];
        cij[idx] = es[j] * inv;
    }
}

// ---------------------------------------------------------------------------
extern "C" void kernel_launch(void* const* d_in, const int* in_sizes, int n_in,
                              void* d_out, int out_size, void* d_ws, size_t ws_size,
                              hipStream_t stream)
{
    const float* x = (const float*)d_in[0];
    const float* W = (const float*)d_in[1];
    float* out = (float*)d_out;
    float* ws  = (float*)d_ws;

    const size_t misc = 4 * 11520 + 2 * 40960 + 2 * 46080;  // b1,b2,c2,c3,v1,v2,dbp0,dbp1
    const size_t need128 = (1474560UL + 128UL * 40960 + 16UL * 40960 + misc) * 4;
    const size_t need64  = (1474560UL +  64UL * 40960 +  8UL * 40960 + misc) * 4;
    int mode = (ws_size >= need128) ? 2 : (ws_size >= need64) ? 1 : 0;
    const int KB  = (mode == 2) ? 128 : (mode == 1) ? 64 : 32;
    const int nsg = KB / 8;

    float* Wp     = (mode > 0) ? ws : nullptr;
    float* s_part = (mode > 0) ? ws + 1474560 : ws;
    float* part2  = s_part + (size_t)KB * 40960;
    float* b1   = part2 + (size_t)nsg * 40960;
    float* b2   = b1 + 11520;
    float* c2   = b2 + 11520;
    float* c3   = c2 + 11520;
    float* v1   = c3 + 11520;
    float* v2   = v1 + 40960;
    float* dbp0 = v2 + 40960;
    float* dbp1 = dbp0 + 46080;

    auto run_s = [&](const float* cwv) {
        if (mode == 2) {
            k_scale<<<576, 256, 0, stream>>>(W, cwv, Wp);
            k_s3<72><<<8 * 128, 128, 0, stream>>>(x, Wp, s_part);
        } else if (mode == 1) {
            k_scale<<<576, 256, 0, stream>>>(W, cwv, Wp);
            k_s3<144><<<8 * 64, 128, 0, stream>>>(x, Wp, s_part);
        } else {
            k_s_legacy<<<16 * KB, 128, 0, stream>>>(x, W, cwv, s_part, KB);
        }
    };

    // ---- iteration 1 (c uniform = 1/1152) ----
    run_s(nullptr);
    k_red<<<40 * nsg, 256, 0, stream>>>(s_part, part2, nsg);
    k_vfin<<<160, 256, 0, stream>>>(part2, v1, nsg);
    k_a<<<2304, 128, 0, stream>>>(x, v1, W, dbp0);
    k_sm<<<10, 128, 0, stream>>>(nullptr, dbp0, b1, c2);

    // ---- iteration 2 ----
    run_s(c2);
    k_red<<<40 * nsg, 256, 0, stream>>>(s_part, part2, nsg);
    k_vfin<<<160, 256, 0, stream>>>(part2, v2, nsg);
    k_a<<<2304, 128, 0, stream>>>(x, v2, W, dbp1);
    k_sm<<<10, 128, 0, stream>>>(b1, dbp1, b2, c3);

    // ---- iteration 3 + outputs ----
    run_s(c3);
    k_red<<<40 * nsg, 256, 0, stream>>>(s_part, part2, nsg);
    k_vfin<<<160, 256, 0, stream>>>(part2, out, nsg);
    k_copy<<<2880, 256, 0, stream>>>(c3, out);
}